// Round 3
// baseline (595.759 us; speedup 1.0000x reference)
//
#include <hip/hip_runtime.h>
#include <math.h>

#define NS 4096
#define NV 65536
#define DDIM 128
#define EPSV 1e-6f
#define NCHUNK 16
#define TILES_PER_CHUNK 32
#define NTILE 512
#define FLTMAX 3.402823466e+38f
#define IMAX 0x7fffffff

// ws layout, 4-byte units unless noted
#define XSQ_F    0              // 4096 floats
#define XSUM_F   4096           // 4096 floats
#define PART_F   8192           // float4 per (sample, chunk): 4096*16*4 floats -> ends 270336
#define D12_F    270336         // float2 per sample: 8192 floats -> ends 278528
#define T12_I    278528         // int2 per sample: 8192 ints -> ends 286720
#define CELL1_I  286720         // 4096 ints
#define CELL2_I  290816         // 4096 ints -> ends 294912 (< 401408 cap)
#define WS_TILED_BYTE 1605632   // tiled V region (bytes)
#define TILE_BYTES 65536        // 8 s x 2 split x 2 q x 128 m x 16B
#define TILE_STRIDE 66560       // + 1KB cj slot (512B cj + pad)

typedef __attribute__((ext_vector_type(8)))  __bf16        bf16x8;
typedef __attribute__((ext_vector_type(8)))  unsigned short ush8;
typedef __attribute__((ext_vector_type(4)))  unsigned short ush4;
typedef __attribute__((ext_vector_type(16))) float          f32x16;

__device__ __forceinline__ unsigned short f2bf(float x) {
    unsigned u = __builtin_bit_cast(unsigned, x);
    u += 0x7FFFu + ((u >> 16) & 1u);      // RNE
    return (unsigned short)(u >> 16);
}
__device__ __forceinline__ float bf2f(unsigned short h) {
    unsigned u = ((unsigned)h) << 16;
    return __builtin_bit_cast(float, u);
}

__device__ __forceinline__ void merge2t(float& d1, int& i1, float& d2, int& i2,
                                        float d, int i) {
    bool b1 = (d < d1) || (d == d1 && i < i1);
    bool b2 = (d < d2) || (d == d2 && i < i2);
    if (b1) { d2 = d1; i2 = i1; d1 = d; i1 = i; }
    else if (b2) { d2 = d; i2 = i; }
}

// convert one sample row (float32, global) into LDS hi/lo fragments at local
// row slot `row`. Layout: (((s*2+h)*2+q)*128 + row)*16 + j0*2. Deterministic:
// identical bytes for identical sample in K2 and K4.
__device__ __forceinline__ void cvt_sample_piece(const float4* __restrict__ s4,
                                                 int srcrow, int row, int kq,
                                                 char* lds) {
    float4 xv = s4[(size_t)srcrow * 32 + kq];
    int k0 = kq * 4, sI = k0 >> 4, qI = (k0 >> 3) & 1, j0 = k0 & 7;
    float xs[4] = {xv.x, xv.y, xv.z, xv.w};
    ush4 h, l;
    #pragma unroll
    for (int e = 0; e < 4; e++) {
        float y = -2.0f * xs[e];
        unsigned short hh = f2bf(y);
        h[e] = hh;
        l[e] = f2bf(y - bf2f(hh));
    }
    *(ush4*)(lds + ((((sI * 2 + 0) * 2 + qI) * 128) + row) * 16 + j0 * 2) = h;
    *(ush4*)(lds + ((((sI * 2 + 1) * 2 + qI) * 128) + row) * 16 + j0 * 2) = l;
}

// Shared per-tile MFMA chain (bit-exact between K2 and K4):
// A = V codes (global, tiled region), B = samples (LDS). acc init = cj.
// acc[sg][r]: code = w*32 + (r&3) + 8*(r>>2) + 4*qb, sample = sg*32 + l31.
__device__ __forceinline__ void tile_mfma_flip(const char* __restrict__ tsrc,
                                               const char* __restrict__ lds,
                                               int w, int qb, int l31,
                                               f32x16 acc[4]) {
    ush8 ah[8], al[8];
    #pragma unroll
    for (int s = 0; s < 8; s++) {
        ah[s] = *(const ush8*)(tsrc + (size_t)((((s * 2 + 0) * 2 + qb) * 128) + w * 32 + l31) * 16);
        al[s] = *(const ush8*)(tsrc + (size_t)((((s * 2 + 1) * 2 + qb) * 128) + w * 32 + l31) * 16);
    }
    const char* cjb = tsrc + TILE_BYTES + (size_t)(w * 32 + 4 * qb) * 4;
    float4 cj0 = *(const float4*)(cjb);
    float4 cj1 = *(const float4*)(cjb + 32);
    float4 cj2 = *(const float4*)(cjb + 64);
    float4 cj3 = *(const float4*)(cjb + 96);
    #pragma unroll
    for (int sg = 0; sg < 4; sg++) {
        acc[sg][0] = cj0.x;  acc[sg][1] = cj0.y;  acc[sg][2] = cj0.z;  acc[sg][3] = cj0.w;
        acc[sg][4] = cj1.x;  acc[sg][5] = cj1.y;  acc[sg][6] = cj1.z;  acc[sg][7] = cj1.w;
        acc[sg][8] = cj2.x;  acc[sg][9] = cj2.y;  acc[sg][10] = cj2.z; acc[sg][11] = cj2.w;
        acc[sg][12] = cj3.x; acc[sg][13] = cj3.y; acc[sg][14] = cj3.z; acc[sg][15] = cj3.w;
    }
    #pragma unroll
    for (int s = 0; s < 8; s++) {
        bf16x8 a_h = __builtin_bit_cast(bf16x8, ah[s]);
        bf16x8 a_l = __builtin_bit_cast(bf16x8, al[s]);
        #pragma unroll
        for (int sg = 0; sg < 4; sg++) {
            bf16x8 b_h = *(const bf16x8*)(lds + (size_t)((((s * 2 + 0) * 2 + qb) * 128) + sg * 32 + l31) * 16);
            bf16x8 b_l = *(const bf16x8*)(lds + (size_t)((((s * 2 + 1) * 2 + qb) * 128) + sg * 32 + l31) * 16);
            acc[sg] = __builtin_amdgcn_mfma_f32_32x32x16_bf16(a_h, b_h, acc[sg], 0, 0, 0);
            acc[sg] = __builtin_amdgcn_mfma_f32_32x32x16_bf16(a_h, b_l, acc[sg], 0, 0, 0);
            acc[sg] = __builtin_amdgcn_mfma_f32_32x32x16_bf16(a_l, b_h, acc[sg], 0, 0, 0);
        }
    }
}

// ---- K1: prep. Blocks [0,512): V tile -> LDS f32 stage -> coalesced tiled
//          bf16 hi/lo + cj slot. Blocks [512,1536): sample row stats ----
__global__ void vq_prep(const float* __restrict__ samples,
                        const float* __restrict__ V,
                        char* __restrict__ ws) {
    __shared__ float tf[128 * 132];   // stride 132 floats: 16B-aligned rows, conflict-light
    float* ws_f = (float*)ws;
    const int b = blockIdx.x;
    const int tid = threadIdx.x;
    if (b >= NV / 128) {
        int row = (b - NV / 128) * 4 + (tid >> 6);
        int lane = tid & 63;
        float2 v = ((const float2*)(samples + (size_t)row * DDIM))[lane];
        float s = v.x + v.y;
        float q = v.x * v.x + v.y * v.y;
        #pragma unroll
        for (int off = 32; off >= 1; off >>= 1) {
            s += __shfl_xor(s, off);
            q += __shfl_xor(q, off);
        }
        if (lane == 0) { ws_f[XSQ_F + row] = q; ws_f[XSUM_F + row] = s; }
        return;
    }
    const int tile = b;
    char* dst = ws + WS_TILED_BYTE + (size_t)tile * TILE_STRIDE;
    const float4* v4 = (const float4*)V;
    // stage f32 tile (coalesced reads) + cj via 32-lane shfl reduce
    #pragma unroll
    for (int i = 0; i < 16; i++) {
        int flat = i * 256 + tid;
        int row = flat >> 5;
        int c4 = flat & 31;
        float4 g = v4[(size_t)(tile * 128 + row) * 32 + c4];
        *(float4*)&tf[row * 132 + c4 * 4] = g;
        float s = g.x + g.y + g.z + g.w;
        float q2 = g.x * g.x + g.y * g.y + g.z * g.z + g.w * g.w;
        #pragma unroll
        for (int off = 16; off >= 1; off >>= 1) {
            s += __shfl_xor(s, off);
            q2 += __shfl_xor(q2, off);
        }
        if ((tid & 31) == 0)
            *(float*)(dst + TILE_BYTES + row * 4) = q2 - 2.0f * EPSV * s;   // cj
    }
    __syncthreads();
    // convert: task (s,q,row) -> two coalesced 16B stores (h, l fragments)
    #pragma unroll
    for (int i = 0; i < 8; i++) {
        int task = i * 256 + tid;
        int row = task & 127;
        int sq = task >> 7;            // 0..15
        int s = sq >> 1, q = sq & 1;
        float4 lo = *(const float4*)&tf[row * 132 + s * 16 + q * 8];
        float4 hi = *(const float4*)&tf[row * 132 + s * 16 + q * 8 + 4];
        float xs[8] = {lo.x, lo.y, lo.z, lo.w, hi.x, hi.y, hi.z, hi.w};
        ush8 h, l;
        #pragma unroll
        for (int j = 0; j < 8; j++) {
            unsigned short hh = f2bf(xs[j]);
            h[j] = hh;
            l[j] = f2bf(xs[j] - bf2f(hh));
        }
        *(ush8*)(dst + (size_t)((((s * 2 + 0) * 2 + q) * 128) + row) * 16) = h;
        *(ush8*)(dst + (size_t)((((s * 2 + 1) * 2 + q) * 128) + row) * 16) = l;
    }
}

// ---- K2: flipped GEMM. Samples in LDS (read-only after init, NO barriers in
// K-loop), V streamed global->VGPR. All 4 waves cover the SAME 128 samples
// (different code blocks) -> cross-wave merge via LDS before the part write. ----
__global__ __launch_bounds__(256, 2)
void vq_gemm_topk(const float* __restrict__ samples, char* __restrict__ ws) {
    __shared__ __align__(16) char lds[TILE_BYTES];
    __shared__ float4 pmerge[4][128];
    const int tid = threadIdx.x;
    const int w = tid >> 6, lane = tid & 63;
    const int l31 = lane & 31, qb = lane >> 5;
    // XCD-affine mapping: 2 chunks per XCD (assumes blockIdx%8 ~ XCD; perf-only)
    const int bid = blockIdx.x;
    const int g = bid >> 3;
    const int chunk = (bid & 7) * 2 + (g >> 5);
    const int st = g & 31;

    // convert this block's 128 samples into LDS (B operand, -2x hi/lo)
    const float4* s4 = (const float4*)samples;
    #pragma unroll
    for (int i = 0; i < 16; i++) {
        int flat = i * 256 + tid;
        int row = flat >> 5, kq = flat & 31;
        cvt_sample_piece(s4, st * 128 + row, row, kq, lds);
    }
    __syncthreads();

    float D1[4], D2[4];
    int T1[4], T2[4];
    #pragma unroll
    for (int sg = 0; sg < 4; sg++) { D1[sg] = FLTMAX; D2[sg] = FLTMAX; T1[sg] = IMAX; T2[sg] = IMAX; }

    const char* vbase = ws + WS_TILED_BYTE;
    #pragma unroll 1
    for (int it = 0; it < TILES_PER_CHUNK; it++) {
        const int tile = chunk * TILES_PER_CHUNK + it;
        const char* tsrc = vbase + (size_t)tile * TILE_STRIDE;
        f32x16 acc[4];
        tile_mfma_flip(tsrc, lds, w, qb, l31, acc);
        #pragma unroll
        for (int sg = 0; sg < 4; sg++) {
            float t1 = FLTMAX, t2 = FLTMAX;
            #pragma unroll
            for (int r = 0; r < 16; r++) {
                float v = acc[sg][r];
                t2 = fminf(t2, fmaxf(t1, v));
                t1 = fminf(t1, v);
            }
            // merge tile-local (t1,t2,tile) into running (D1,T1,D2,T2);
            // tile strictly increasing -> ties keep the earlier tile
            bool c1 = t1 < D1[sg];
            float m1 = fminf(D1[sg], t2);
            float m2 = fminf(D2[sg], t1);
            int T2a = (t2 < D1[sg]) ? tile : T1[sg];
            int T2b = (t1 < D2[sg]) ? tile : T2[sg];
            D2[sg] = c1 ? m1 : m2;
            T2[sg] = c1 ? T2a : T2b;
            T1[sg] = c1 ? tile : T1[sg];
            D1[sg] = c1 ? t1 : D1[sg];
        }
    }

    // cross-qb merge (other half-wave: same samples, other 16 codes of w's block)
    #pragma unroll
    for (int sg = 0; sg < 4; sg++) {
        float d1 = D1[sg], d2 = D2[sg];
        int t1 = T1[sg], t2 = T2[sg];
        float od1 = __shfl_xor(d1, 32), od2 = __shfl_xor(d2, 32);
        int   ot1 = __shfl_xor(t1, 32), ot2 = __shfl_xor(t2, 32);
        merge2t(d1, t1, d2, t2, od1, ot1);
        merge2t(d1, t1, d2, t2, od2, ot2);
        if (qb == 0)
            pmerge[w][sg * 32 + l31] = make_float4(d1, d2, (float)t1, (float)t2);
    }
    __syncthreads();
    // cross-wave merge: waves cover disjoint code blocks of the same samples
    if (tid < 128) {
        float4 p0 = pmerge[0][tid];
        float d1 = p0.x, d2 = p0.y;
        int t1 = (int)p0.z, t2 = (int)p0.w;
        #pragma unroll
        for (int ww = 1; ww < 4; ww++) {
            float4 p = pmerge[ww][tid];
            merge2t(d1, t1, d2, t2, p.x, (int)p.z);
            merge2t(d1, t1, d2, t2, p.y, (int)p.w);
        }
        float4* part = (float4*)((float*)ws + PART_F);
        part[(size_t)(st * 128 + tid) * NCHUNK + chunk] =
            make_float4(d1, d2, (float)t1, (float)t2);
    }
}

// ---- K3: merge chunk partials -> global top-2 values + tile ids; write 'a' ----
__global__ void vq_merge(float* __restrict__ ws_f, float* __restrict__ out) {
    const int m = blockIdx.x * 256 + threadIdx.x;
    int* ws_i = (int*)ws_f;
    const float4* part = (const float4*)(ws_f + PART_F);
    float d1 = FLTMAX, d2 = FLTMAX;
    int t1 = IMAX, t2 = IMAX;
    #pragma unroll
    for (int c = 0; c < NCHUNK; c++) {
        float4 p = part[(size_t)m * NCHUNK + c];
        merge2t(d1, t1, d2, t2, p.x, (int)p.z);
        merge2t(d1, t1, d2, t2, p.y, (int)p.w);
    }
    ((float2*)(ws_f + D12_F))[m] = make_float2(d1, d2);
    ((int2*)(ws_i + T12_I))[m] = make_int2(t1, t2);
    ws_i[CELL1_I + m] = IMAX;
    ws_i[CELL2_I + m] = IMAX;
    float ci = ws_f[XSQ_F + m] + 2.0f * EPSV * ws_f[XSUM_F + m] + (float)DDIM * EPSV * EPSV;
    out[2 * NS + m] = expf(-sqrtf(fmaxf(ci + d1, 0.0f)));
}

// ---- K4: per-tile bit-exact rescan. One block per tile; self-compacts the
// sample list; indices by float equality; atomicMin 2-slot == ref tiebreak ----
__global__ __launch_bounds__(256)
void vq_recover(const float* __restrict__ samples, char* __restrict__ ws) {
    __shared__ __align__(16) char sbuf[TILE_BYTES];
    __shared__ int list[NS];
    __shared__ int lcnt;
    const int tid = threadIdx.x;
    const int w = tid >> 6, lane = tid & 63;
    const int l31 = lane & 31, qb = lane >> 5;
    const int tile = blockIdx.x;
    int* ws_i = (int*)ws;
    float* ws_f = (float*)ws;

    if (tid == 0) lcnt = 0;
    __syncthreads();
    const int2* t12 = (const int2*)(ws_i + T12_I);
    for (int i = tid; i < NS; i += 256) {
        int2 t = t12[i];
        if (t.x == tile || t.y == tile) {
            int p = atomicAdd(&lcnt, 1);
            list[p] = i;
        }
    }
    __syncthreads();
    const int cnt = lcnt;
    if (cnt == 0) return;

    const char* tsrc = ws + WS_TILED_BYTE + (size_t)tile * TILE_STRIDE;
    const float4* s4 = (const float4*)samples;
    const float2* d12 = (const float2*)(ws_f + D12_F);
    const float nanf_ = __int_as_float(0x7fc00000);

    for (int b0 = 0; b0 < cnt; b0 += 128) {
        __syncthreads();   // everyone done with previous sbuf contents
        #pragma unroll
        for (int i = 0; i < 16; i++) {
            int flat = i * 256 + tid;
            int row = flat >> 5, kq = flat & 31;
            int srow = (b0 + row < cnt) ? list[b0 + row] : 0;
            cvt_sample_piece(s4, srow, row, kq, sbuf);
        }
        __syncthreads();
        f32x16 acc[4];
        tile_mfma_flip(tsrc, sbuf, w, qb, l31, acc);
        #pragma unroll
        for (int sg = 0; sg < 4; sg++) {
            int li = b0 + sg * 32 + l31;
            bool valid = li < cnt;
            int m = valid ? list[li] : 0;
            float d1t = nanf_, d2t = nanf_;
            if (valid) {
                float2 dt = d12[m];
                d1t = dt.x; d2t = dt.y;
            }
            #pragma unroll
            for (int r = 0; r < 16; r++) {
                float v = acc[sg][r];
                int idx = tile * 128 + w * 32 + (r & 3) + 8 * (r >> 2) + 4 * qb;
                if (v == d1t) {
                    int old = atomicMin(&ws_i[CELL1_I + m], idx);
                    int loser = old > idx ? old : idx;
                    atomicMin(&ws_i[CELL2_I + m], loser);
                } else if (v == d2t) {
                    atomicMin(&ws_i[CELL2_I + m], idx);
                }
            }
        }
    }
}

// ---- K5: write index outputs ----
__global__ void vq_finalize(const char* __restrict__ ws, float* __restrict__ out) {
    const int m = blockIdx.x * 256 + threadIdx.x;
    const int* ws_i = (const int*)ws;
    out[m]      = (float)ws_i[CELL1_I + m];
    out[NS + m] = (float)ws_i[CELL2_I + m];
}

extern "C" void kernel_launch(void* const* d_in, const int* in_sizes, int n_in,
                              void* d_out, int out_size, void* d_ws, size_t ws_size,
                              hipStream_t stream) {
    (void)in_sizes; (void)n_in; (void)out_size; (void)ws_size;
    const float* samples = (const float*)d_in[0];
    const float* V = (const float*)d_in[1];
    float* out = (float*)d_out;
    float* ws_f = (float*)d_ws;
    char*  ws_b = (char*)d_ws;

    vq_prep<<<dim3(NV / 128 + NS / 4), 256, 0, stream>>>(samples, V, ws_b);
    vq_gemm_topk<<<dim3((NS / 128) * NCHUNK), 256, 0, stream>>>(samples, ws_b);
    vq_merge<<<dim3(NS / 256), 256, 0, stream>>>(ws_f, out);
    vq_recover<<<dim3(NTILE), 256, 0, stream>>>(samples, ws_b);
    vq_finalize<<<dim3(NS / 256), 256, 0, stream>>>(ws_b, out);
}

// Round 4
// 493.011 us; speedup vs baseline: 1.2084x; 1.2084x over previous
//
#include <hip/hip_runtime.h>
#include <math.h>

#define NS 4096
#define NV 65536
#define DDIM 128
#define EPSV 1e-6f
#define NCHUNK 16
#define TILES_PER_CHUNK 32
#define NTILE 512
#define FLTMAX 3.402823466e+38f
#define IMAX 0x7fffffff

// ws layout, 4-byte units unless noted
#define XSQ_F    0              // 4096 floats
#define XSUM_F   4096           // 4096 floats
#define PART_F   8192           // float4 per (sample, chunk): 4096*16*4 floats -> ends 270336
#define D12_F    270336         // float2 per sample: 8192 floats -> ends 278528
#define T12_I    278528         // int2 per sample: 8192 ints -> ends 286720
#define CELL1_I  286720         // 4096 ints
#define CELL2_I  290816         // 4096 ints -> ends 294912 (< 401408 cap)
#define WS_TILED_BYTE 1605632   // tiled V region (bytes)
#define TILE_BYTES 65536        // 8 s x 2 split x 2 q x 128 m x 16B
#define TILE_STRIDE 66560       // + 1KB cj slot (512B cj + pad)

typedef __attribute__((ext_vector_type(8)))  __bf16        bf16x8;
typedef __attribute__((ext_vector_type(8)))  unsigned short ush8;
typedef __attribute__((ext_vector_type(4)))  unsigned short ush4;
typedef __attribute__((ext_vector_type(16))) float          f32x16;

__device__ __forceinline__ unsigned short f2bf(float x) {
    unsigned u = __builtin_bit_cast(unsigned, x);
    u += 0x7FFFu + ((u >> 16) & 1u);      // RNE
    return (unsigned short)(u >> 16);
}
__device__ __forceinline__ float bf2f(unsigned short h) {
    unsigned u = ((unsigned)h) << 16;
    return __builtin_bit_cast(float, u);
}

__device__ __forceinline__ void merge2t(float& d1, int& i1, float& d2, int& i2,
                                        float d, int i) {
    bool b1 = (d < d1) || (d == d1 && i < i1);
    bool b2 = (d < d2) || (d == d2 && i < i2);
    if (b1) { d2 = d1; i2 = i1; d1 = d; i1 = i; }
    else if (b2) { d2 = d; i2 = i; }
}

// convert one sample row (float32, global) into LDS hi/lo fragments at local
// row slot `row`. Layout: (((s*2+h)*2+q)*128 + row)*16 + j0*2. Deterministic:
// identical bytes for identical sample in K2 and K4.
__device__ __forceinline__ void cvt_sample_piece(const float4* __restrict__ s4,
                                                 int srcrow, int row, int kq,
                                                 char* lds) {
    float4 xv = s4[(size_t)srcrow * 32 + kq];
    int k0 = kq * 4, sI = k0 >> 4, qI = (k0 >> 3) & 1, j0 = k0 & 7;
    float xs[4] = {xv.x, xv.y, xv.z, xv.w};
    ush4 h, l;
    #pragma unroll
    for (int e = 0; e < 4; e++) {
        float y = -2.0f * xs[e];
        unsigned short hh = f2bf(y);
        h[e] = hh;
        l[e] = f2bf(y - bf2f(hh));
    }
    *(ush4*)(lds + ((((sI * 2 + 0) * 2 + qI) * 128) + row) * 16 + j0 * 2) = h;
    *(ush4*)(lds + ((((sI * 2 + 1) * 2 + qI) * 128) + row) * 16 + j0 * 2) = l;
}

// A-fragment (V codes + cj) for one tile, held in VGPRs.
struct AFrag {
    ush8 ah[8], al[8];
    float4 cj0, cj1, cj2, cj3;
};

__device__ __forceinline__ void afrag_load(const char* __restrict__ tsrc,
                                           int w, int qb, int l31, AFrag& f) {
    #pragma unroll
    for (int s = 0; s < 8; s++) {
        f.ah[s] = *(const ush8*)(tsrc + (size_t)((((s * 2 + 0) * 2 + qb) * 128) + w * 32 + l31) * 16);
        f.al[s] = *(const ush8*)(tsrc + (size_t)((((s * 2 + 1) * 2 + qb) * 128) + w * 32 + l31) * 16);
    }
    const char* cjb = tsrc + TILE_BYTES + (size_t)(w * 32 + 4 * qb) * 4;
    f.cj0 = *(const float4*)(cjb);
    f.cj1 = *(const float4*)(cjb + 32);
    f.cj2 = *(const float4*)(cjb + 64);
    f.cj3 = *(const float4*)(cjb + 96);
}

// MFMA chain (identical statement order in K2 and K4 -> bit-exact results).
// acc[sg][r]: code = w*32 + (r&3) + 8*(r>>2) + 4*qb, sample = sg*32 + l31.
__device__ __forceinline__ void afrag_compute(const AFrag& f,
                                              const char* __restrict__ lds,
                                              int qb, int l31, f32x16 acc[4]) {
    #pragma unroll
    for (int sg = 0; sg < 4; sg++) {
        acc[sg][0] = f.cj0.x;  acc[sg][1] = f.cj0.y;  acc[sg][2] = f.cj0.z;  acc[sg][3] = f.cj0.w;
        acc[sg][4] = f.cj1.x;  acc[sg][5] = f.cj1.y;  acc[sg][6] = f.cj1.z;  acc[sg][7] = f.cj1.w;
        acc[sg][8] = f.cj2.x;  acc[sg][9] = f.cj2.y;  acc[sg][10] = f.cj2.z; acc[sg][11] = f.cj2.w;
        acc[sg][12] = f.cj3.x; acc[sg][13] = f.cj3.y; acc[sg][14] = f.cj3.z; acc[sg][15] = f.cj3.w;
    }
    #pragma unroll
    for (int s = 0; s < 8; s++) {
        bf16x8 a_h = __builtin_bit_cast(bf16x8, f.ah[s]);
        bf16x8 a_l = __builtin_bit_cast(bf16x8, f.al[s]);
        #pragma unroll
        for (int sg = 0; sg < 4; sg++) {
            bf16x8 b_h = *(const bf16x8*)(lds + (size_t)((((s * 2 + 0) * 2 + qb) * 128) + sg * 32 + l31) * 16);
            bf16x8 b_l = *(const bf16x8*)(lds + (size_t)((((s * 2 + 1) * 2 + qb) * 128) + sg * 32 + l31) * 16);
            acc[sg] = __builtin_amdgcn_mfma_f32_32x32x16_bf16(a_h, b_h, acc[sg], 0, 0, 0);
            acc[sg] = __builtin_amdgcn_mfma_f32_32x32x16_bf16(a_h, b_l, acc[sg], 0, 0, 0);
            acc[sg] = __builtin_amdgcn_mfma_f32_32x32x16_bf16(a_l, b_h, acc[sg], 0, 0, 0);
        }
    }
}

// Combined helper used by K4 (recover): same FP order as K2's load+compute.
__device__ __forceinline__ void tile_mfma_flip(const char* __restrict__ tsrc,
                                               const char* __restrict__ lds,
                                               int w, int qb, int l31,
                                               f32x16 acc[4]) {
    AFrag f;
    afrag_load(tsrc, w, qb, l31, f);
    afrag_compute(f, lds, qb, l31, acc);
}

// per-tile value+tile-id top-2 merge (tile strictly increasing -> ties keep
// the earlier tile)
__device__ __forceinline__ void tile_top2(const f32x16 acc[4], int tile,
                                          float D1[4], float D2[4],
                                          int T1[4], int T2[4]) {
    #pragma unroll
    for (int sg = 0; sg < 4; sg++) {
        float t1 = FLTMAX, t2 = FLTMAX;
        #pragma unroll
        for (int r = 0; r < 16; r++) {
            float v = acc[sg][r];
            t2 = fminf(t2, fmaxf(t1, v));
            t1 = fminf(t1, v);
        }
        bool c1 = t1 < D1[sg];
        float m1 = fminf(D1[sg], t2);
        float m2 = fminf(D2[sg], t1);
        int T2a = (t2 < D1[sg]) ? tile : T1[sg];
        int T2b = (t1 < D2[sg]) ? tile : T2[sg];
        D2[sg] = c1 ? m1 : m2;
        T2[sg] = c1 ? T2a : T2b;
        T1[sg] = c1 ? tile : T1[sg];
        D1[sg] = c1 ? t1 : D1[sg];
    }
}

// ---- K1: prep. Blocks [0,512): V tile -> LDS f32 stage -> coalesced tiled
//          bf16 hi/lo + cj slot. Blocks [512,1536): sample row stats ----
__global__ void vq_prep(const float* __restrict__ samples,
                        const float* __restrict__ V,
                        char* __restrict__ ws) {
    __shared__ float tf[128 * 132];   // stride 132 floats: 16B-aligned rows, conflict-free
    float* ws_f = (float*)ws;
    const int b = blockIdx.x;
    const int tid = threadIdx.x;
    if (b >= NV / 128) {
        int row = (b - NV / 128) * 4 + (tid >> 6);
        int lane = tid & 63;
        float2 v = ((const float2*)(samples + (size_t)row * DDIM))[lane];
        float s = v.x + v.y;
        float q = v.x * v.x + v.y * v.y;
        #pragma unroll
        for (int off = 32; off >= 1; off >>= 1) {
            s += __shfl_xor(s, off);
            q += __shfl_xor(q, off);
        }
        if (lane == 0) { ws_f[XSQ_F + row] = q; ws_f[XSUM_F + row] = s; }
        return;
    }
    const int tile = b;
    char* dst = ws + WS_TILED_BYTE + (size_t)tile * TILE_STRIDE;
    const float4* v4 = (const float4*)V;
    // stage f32 tile (coalesced reads) + cj via 32-lane shfl reduce
    #pragma unroll
    for (int i = 0; i < 16; i++) {
        int flat = i * 256 + tid;
        int row = flat >> 5;
        int c4 = flat & 31;
        float4 g = v4[(size_t)(tile * 128 + row) * 32 + c4];
        *(float4*)&tf[row * 132 + c4 * 4] = g;
        float s = g.x + g.y + g.z + g.w;
        float q2 = g.x * g.x + g.y * g.y + g.z * g.z + g.w * g.w;
        #pragma unroll
        for (int off = 16; off >= 1; off >>= 1) {
            s += __shfl_xor(s, off);
            q2 += __shfl_xor(q2, off);
        }
        if ((tid & 31) == 0)
            *(float*)(dst + TILE_BYTES + row * 4) = q2 - 2.0f * EPSV * s;   // cj
    }
    __syncthreads();
    // convert: task (s,q,row) -> two coalesced 16B stores (h, l fragments)
    #pragma unroll
    for (int i = 0; i < 8; i++) {
        int task = i * 256 + tid;
        int row = task & 127;
        int sq = task >> 7;            // 0..15
        int s = sq >> 1, q = sq & 1;
        float4 lo = *(const float4*)&tf[row * 132 + s * 16 + q * 8];
        float4 hi = *(const float4*)&tf[row * 132 + s * 16 + q * 8 + 4];
        float xs[8] = {lo.x, lo.y, lo.z, lo.w, hi.x, hi.y, hi.z, hi.w};
        ush8 h, l;
        #pragma unroll
        for (int j = 0; j < 8; j++) {
            unsigned short hh = f2bf(xs[j]);
            h[j] = hh;
            l[j] = f2bf(xs[j] - bf2f(hh));
        }
        *(ush8*)(dst + (size_t)((((s * 2 + 0) * 2 + q) * 128) + row) * 16) = h;
        *(ush8*)(dst + (size_t)((((s * 2 + 1) * 2 + q) * 128) + row) * 16) = l;
    }
}

// ---- K2: flipped GEMM. Samples in LDS (read-only after init, NO barriers in
// K-loop), V streamed global->VGPR with ping-pong prefetch (tile t+1's loads
// issued before tile t's MFMA chain). LDS padded past 80KB to force
// 1 block/CU: per XCD only 32 blocks resident -> one 2.13MB chunk L2-fits. ----
__global__ __launch_bounds__(256, 1)
void vq_gemm_topk(const float* __restrict__ samples, char* __restrict__ ws) {
    __shared__ __align__(16) char lds[TILE_BYTES + 24576];  // pad -> 1 block/CU
    __shared__ float4 pmerge[4][128];
    const int tid = threadIdx.x;
    const int w = tid >> 6, lane = tid & 63;
    const int l31 = lane & 31, qb = lane >> 5;
    // XCD-affine mapping: blocks 0..255 -> chunk 2*(bid%8), 256..511 -> +1.
    const int bid = blockIdx.x;
    const int g = bid >> 3;
    const int chunk = (bid & 7) * 2 + (g >> 5);
    const int st = g & 31;

    // convert this block's 128 samples into LDS (B operand, -2x hi/lo)
    const float4* s4 = (const float4*)samples;
    #pragma unroll
    for (int i = 0; i < 16; i++) {
        int flat = i * 256 + tid;
        int row = flat >> 5, kq = flat & 31;
        cvt_sample_piece(s4, st * 128 + row, row, kq, lds);
    }
    __syncthreads();

    float D1[4], D2[4];
    int T1[4], T2[4];
    #pragma unroll
    for (int sg = 0; sg < 4; sg++) { D1[sg] = FLTMAX; D2[sg] = FLTMAX; T1[sg] = IMAX; T2[sg] = IMAX; }

    const char* vbase = ws + WS_TILED_BYTE;
    const int tbase = chunk * TILES_PER_CHUNK;

    AFrag fA, fB;
    afrag_load(vbase + (size_t)tbase * TILE_STRIDE, w, qb, l31, fA);
    #pragma unroll 1
    for (int it2 = 0; it2 < TILES_PER_CHUNK / 2; it2++) {
        const int t0 = tbase + 2 * it2;
        afrag_load(vbase + (size_t)(t0 + 1) * TILE_STRIDE, w, qb, l31, fB);
        f32x16 acc[4];
        afrag_compute(fA, lds, qb, l31, acc);
        tile_top2(acc, t0, D1, D2, T1, T2);
        if (it2 < TILES_PER_CHUNK / 2 - 1)
            afrag_load(vbase + (size_t)(t0 + 2) * TILE_STRIDE, w, qb, l31, fA);
        afrag_compute(fB, lds, qb, l31, acc);
        tile_top2(acc, t0 + 1, D1, D2, T1, T2);
    }

    // cross-qb merge (other half-wave: same samples, other 16 codes of w's block)
    #pragma unroll
    for (int sg = 0; sg < 4; sg++) {
        float d1 = D1[sg], d2 = D2[sg];
        int t1 = T1[sg], t2 = T2[sg];
        float od1 = __shfl_xor(d1, 32), od2 = __shfl_xor(d2, 32);
        int   ot1 = __shfl_xor(t1, 32), ot2 = __shfl_xor(t2, 32);
        merge2t(d1, t1, d2, t2, od1, ot1);
        merge2t(d1, t1, d2, t2, od2, ot2);
        if (qb == 0)
            pmerge[w][sg * 32 + l31] = make_float4(d1, d2, (float)t1, (float)t2);
    }
    __syncthreads();
    // cross-wave merge: waves cover disjoint code blocks of the same samples
    if (tid < 128) {
        float4 p0 = pmerge[0][tid];
        float d1 = p0.x, d2 = p0.y;
        int t1 = (int)p0.z, t2 = (int)p0.w;
        #pragma unroll
        for (int ww = 1; ww < 4; ww++) {
            float4 p = pmerge[ww][tid];
            merge2t(d1, t1, d2, t2, p.x, (int)p.z);
            merge2t(d1, t1, d2, t2, p.y, (int)p.w);
        }
        float4* part = (float4*)((float*)ws + PART_F);
        part[(size_t)(st * 128 + tid) * NCHUNK + chunk] =
            make_float4(d1, d2, (float)t1, (float)t2);
    }
}

// ---- K3: merge chunk partials -> global top-2 values + tile ids; write 'a' ----
__global__ void vq_merge(float* __restrict__ ws_f, float* __restrict__ out) {
    const int m = blockIdx.x * 256 + threadIdx.x;
    int* ws_i = (int*)ws_f;
    const float4* part = (const float4*)(ws_f + PART_F);
    float d1 = FLTMAX, d2 = FLTMAX;
    int t1 = IMAX, t2 = IMAX;
    #pragma unroll
    for (int c = 0; c < NCHUNK; c++) {
        float4 p = part[(size_t)m * NCHUNK + c];
        merge2t(d1, t1, d2, t2, p.x, (int)p.z);
        merge2t(d1, t1, d2, t2, p.y, (int)p.w);
    }
    ((float2*)(ws_f + D12_F))[m] = make_float2(d1, d2);
    ((int2*)(ws_i + T12_I))[m] = make_int2(t1, t2);
    ws_i[CELL1_I + m] = IMAX;
    ws_i[CELL2_I + m] = IMAX;
    float ci = ws_f[XSQ_F + m] + 2.0f * EPSV * ws_f[XSUM_F + m] + (float)DDIM * EPSV * EPSV;
    out[2 * NS + m] = expf(-sqrtf(fmaxf(ci + d1, 0.0f)));
}

// ---- K4: per-tile bit-exact rescan. One block per tile; self-compacts the
// sample list; indices by float equality; atomicMin 2-slot == ref tiebreak ----
__global__ __launch_bounds__(256)
void vq_recover(const float* __restrict__ samples, char* __restrict__ ws) {
    __shared__ __align__(16) char sbuf[TILE_BYTES];
    __shared__ int list[NS];
    __shared__ int lcnt;
    const int tid = threadIdx.x;
    const int w = tid >> 6, lane = tid & 63;
    const int l31 = lane & 31, qb = lane >> 5;
    const int tile = blockIdx.x;
    int* ws_i = (int*)ws;
    float* ws_f = (float*)ws;

    if (tid == 0) lcnt = 0;
    __syncthreads();
    const int2* t12 = (const int2*)(ws_i + T12_I);
    for (int i = tid; i < NS; i += 256) {
        int2 t = t12[i];
        if (t.x == tile || t.y == tile) {
            int p = atomicAdd(&lcnt, 1);
            list[p] = i;
        }
    }
    __syncthreads();
    const int cnt = lcnt;
    if (cnt == 0) return;

    const char* tsrc = ws + WS_TILED_BYTE + (size_t)tile * TILE_STRIDE;
    const float4* s4 = (const float4*)samples;
    const float2* d12 = (const float2*)(ws_f + D12_F);
    const float nanf_ = __int_as_float(0x7fc00000);

    for (int b0 = 0; b0 < cnt; b0 += 128) {
        __syncthreads();   // everyone done with previous sbuf contents
        #pragma unroll
        for (int i = 0; i < 16; i++) {
            int flat = i * 256 + tid;
            int row = flat >> 5, kq = flat & 31;
            int srow = (b0 + row < cnt) ? list[b0 + row] : 0;
            cvt_sample_piece(s4, srow, row, kq, sbuf);
        }
        __syncthreads();
        f32x16 acc[4];
        tile_mfma_flip(tsrc, sbuf, w, qb, l31, acc);
        #pragma unroll
        for (int sg = 0; sg < 4; sg++) {
            int li = b0 + sg * 32 + l31;
            bool valid = li < cnt;
            int m = valid ? list[li] : 0;
            float d1t = nanf_, d2t = nanf_;
            if (valid) {
                float2 dt = d12[m];
                d1t = dt.x; d2t = dt.y;
            }
            #pragma unroll
            for (int r = 0; r < 16; r++) {
                float v = acc[sg][r];
                int idx = tile * 128 + w * 32 + (r & 3) + 8 * (r >> 2) + 4 * qb;
                if (v == d1t) {
                    int old = atomicMin(&ws_i[CELL1_I + m], idx);
                    int loser = old > idx ? old : idx;
                    atomicMin(&ws_i[CELL2_I + m], loser);
                } else if (v == d2t) {
                    atomicMin(&ws_i[CELL2_I + m], idx);
                }
            }
        }
    }
}

// ---- K5: write index outputs ----
__global__ void vq_finalize(const char* __restrict__ ws, float* __restrict__ out) {
    const int m = blockIdx.x * 256 + threadIdx.x;
    const int* ws_i = (const int*)ws;
    out[m]      = (float)ws_i[CELL1_I + m];
    out[NS + m] = (float)ws_i[CELL2_I + m];
}

extern "C" void kernel_launch(void* const* d_in, const int* in_sizes, int n_in,
                              void* d_out, int out_size, void* d_ws, size_t ws_size,
                              hipStream_t stream) {
    (void)in_sizes; (void)n_in; (void)out_size; (void)ws_size;
    const float* samples = (const float*)d_in[0];
    const float* V = (const float*)d_in[1];
    float* out = (float*)d_out;
    float* ws_f = (float*)d_ws;
    char*  ws_b = (char*)d_ws;

    vq_prep<<<dim3(NV / 128 + NS / 4), 256, 0, stream>>>(samples, V, ws_b);
    vq_gemm_topk<<<dim3((NS / 128) * NCHUNK), 256, 0, stream>>>(samples, ws_b);
    vq_merge<<<dim3(NS / 256), 256, 0, stream>>>(ws_f, out);
    vq_recover<<<dim3(NTILE), 256, 0, stream>>>(samples, ws_b);
    vq_finalize<<<dim3(NS / 256), 256, 0, stream>>>(ws_b, out);
}

// Round 6
// 291.523 us; speedup vs baseline: 2.0436x; 1.6912x over previous
//
#include <hip/hip_runtime.h>
#include <math.h>

#define NS 4096
#define NV 65536
#define DDIM 128
#define EPSV 1e-6f
#define NCHUNK 16
#define TILES_PER_CHUNK 32
#define NTILE 512
#define FLTMAX 3.402823466e+38f
#define IMAX 0x7fffffff

// ws layout, 4-byte units unless noted
#define XSQ_F    0              // 4096 floats
#define XSUM_F   4096           // 4096 floats
#define PART_F   8192           // float4 per (sample, chunk): 4096*16*4 floats -> ends 270336
#define D12_F    270336         // float2 per sample: 8192 floats -> ends 278528
#define T12_I    278528         // int2 per sample: 8192 ints -> ends 286720
#define CELL1_I  286720         // 4096 ints
#define CELL2_I  290816         // 4096 ints -> ends 294912 (< 401408 cap)
#define WS_TILED_BYTE 1605632   // tiled V region (bytes)
#define TILE_BYTES 65536        // 8 s x 2 split x 2 q x 128 m x 16B
#define TILE_STRIDE 66560       // + 1KB cj slot (512B cj + pad)

typedef __attribute__((ext_vector_type(8)))  __bf16        bf16x8;
typedef __attribute__((ext_vector_type(8)))  unsigned short ush8;
typedef __attribute__((ext_vector_type(4)))  unsigned short ush4;
typedef __attribute__((ext_vector_type(16))) float          f32x16;

typedef const __attribute__((address_space(1))) unsigned int* gp_t;
typedef __attribute__((address_space(3))) unsigned int*       lp_t;

__device__ __forceinline__ void async_cp16(const void* g, void* l) {
    __builtin_amdgcn_global_load_lds((gp_t)g, (lp_t)l, 16, 0, 0);
}

__device__ __forceinline__ unsigned short f2bf(float x) {
    unsigned u = __builtin_bit_cast(unsigned, x);
    u += 0x7FFFu + ((u >> 16) & 1u);      // RNE
    return (unsigned short)(u >> 16);
}
__device__ __forceinline__ float bf2f(unsigned short h) {
    unsigned u = ((unsigned)h) << 16;
    return __builtin_bit_cast(float, u);
}

__device__ __forceinline__ void merge2t(float& d1, int& i1, float& d2, int& i2,
                                        float d, int i) {
    bool b1 = (d < d1) || (d == d1 && i < i1);
    bool b2 = (d < d2) || (d == d2 && i < i2);
    if (b1) { d2 = d1; i2 = i1; d1 = d; i1 = i; }
    else if (b2) { d2 = d; i2 = i; }
}

// this lane's B fragments: sample row scaled by -2 (exact), hi/lo bf16 split.
// Deterministic: identical results for identical sample row in K2 and K4.
__device__ __forceinline__ void load_bfrag(const float* __restrict__ samples,
                                           int srow, int q, ush8* bh, ush8* bl) {
    const float4* s4 = (const float4*)samples;
    #pragma unroll
    for (int s = 0; s < 8; s++) {
        float4 x0 = s4[(size_t)srow * 32 + s * 4 + q * 2];
        float4 x1 = s4[(size_t)srow * 32 + s * 4 + q * 2 + 1];
        float xs[8] = {x0.x, x0.y, x0.z, x0.w, x1.x, x1.y, x1.z, x1.w};
        #pragma unroll
        for (int j = 0; j < 8; j++) {
            float y = -2.0f * xs[j];
            unsigned short hh = f2bf(y);
            bh[s][j] = hh;
            bl[s][j] = f2bf(y - bf2f(hh));
        }
    }
}

// Shared per-tile MFMA chain (bit-exact between K2 and K4).
// A = V codes (LDS tile), B = samples (VGPR). acc init = cj (from LDS cj slot).
// acc[mi][r]: code row = mi*32 + (r&3) + 8*(r>>2) + 4*q, sample col = l31.
__device__ __forceinline__ void tile_mfma(const char* __restrict__ lds,
                                          const ush8* bh, const ush8* bl,
                                          int q, int l31, f32x16 acc[4]) {
    #pragma unroll
    for (int mi = 0; mi < 4; mi++) {
        const char* cjb = lds + TILE_BYTES + (size_t)(mi * 32 + 4 * q) * 4;
        float4 c0 = *(const float4*)(cjb);
        float4 c1 = *(const float4*)(cjb + 32);
        float4 c2 = *(const float4*)(cjb + 64);
        float4 c3 = *(const float4*)(cjb + 96);
        acc[mi][0] = c0.x;  acc[mi][1] = c0.y;  acc[mi][2] = c0.z;  acc[mi][3] = c0.w;
        acc[mi][4] = c1.x;  acc[mi][5] = c1.y;  acc[mi][6] = c1.z;  acc[mi][7] = c1.w;
        acc[mi][8] = c2.x;  acc[mi][9] = c2.y;  acc[mi][10] = c2.z; acc[mi][11] = c2.w;
        acc[mi][12] = c3.x; acc[mi][13] = c3.y; acc[mi][14] = c3.z; acc[mi][15] = c3.w;
    }
    #pragma unroll
    for (int s = 0; s < 8; s++) {
        bf16x8 bhs = __builtin_bit_cast(bf16x8, bh[s]);
        bf16x8 bls = __builtin_bit_cast(bf16x8, bl[s]);
        #pragma unroll
        for (int mi = 0; mi < 4; mi++) {
            bf16x8 ah = *(const bf16x8*)(lds + (size_t)((((s * 2 + 0) * 2 + q) * 128) + mi * 32 + l31) * 16);
            bf16x8 al = *(const bf16x8*)(lds + (size_t)((((s * 2 + 1) * 2 + q) * 128) + mi * 32 + l31) * 16);
            acc[mi] = __builtin_amdgcn_mfma_f32_32x32x16_bf16(ah, bhs, acc[mi], 0, 0, 0);
            acc[mi] = __builtin_amdgcn_mfma_f32_32x32x16_bf16(ah, bls, acc[mi], 0, 0, 0);
            acc[mi] = __builtin_amdgcn_mfma_f32_32x32x16_bf16(al, bhs, acc[mi], 0, 0, 0);
        }
    }
}

// ---- K1: prep. Blocks [0,512): V tile -> LDS f32 stage -> coalesced tiled
//          bf16 hi/lo + cj slot. Blocks [512,1536): sample row stats ----
__global__ void vq_prep(const float* __restrict__ samples,
                        const float* __restrict__ V,
                        char* __restrict__ ws) {
    __shared__ float tf[128 * 132];   // stride 132 floats: 16B-aligned rows, conflict-light
    float* ws_f = (float*)ws;
    const int b = blockIdx.x;
    const int tid = threadIdx.x;
    if (b >= NV / 128) {
        int row = (b - NV / 128) * 4 + (tid >> 6);
        int lane = tid & 63;
        float2 v = ((const float2*)(samples + (size_t)row * DDIM))[lane];
        float s = v.x + v.y;
        float q = v.x * v.x + v.y * v.y;
        #pragma unroll
        for (int off = 32; off >= 1; off >>= 1) {
            s += __shfl_xor(s, off);
            q += __shfl_xor(q, off);
        }
        if (lane == 0) { ws_f[XSQ_F + row] = q; ws_f[XSUM_F + row] = s; }
        return;
    }
    const int tile = b;
    char* dst = ws + WS_TILED_BYTE + (size_t)tile * TILE_STRIDE;
    const float4* v4 = (const float4*)V;
    // stage f32 tile (coalesced reads) + cj via 32-lane shfl reduce
    #pragma unroll
    for (int i = 0; i < 16; i++) {
        int flat = i * 256 + tid;
        int row = flat >> 5;
        int c4 = flat & 31;
        float4 g = v4[(size_t)(tile * 128 + row) * 32 + c4];
        *(float4*)&tf[row * 132 + c4 * 4] = g;
        float s = g.x + g.y + g.z + g.w;
        float q2 = g.x * g.x + g.y * g.y + g.z * g.z + g.w * g.w;
        #pragma unroll
        for (int off = 16; off >= 1; off >>= 1) {
            s += __shfl_xor(s, off);
            q2 += __shfl_xor(q2, off);
        }
        if ((tid & 31) == 0)
            *(float*)(dst + TILE_BYTES + row * 4) = q2 - 2.0f * EPSV * s;   // cj
    }
    __syncthreads();
    // convert: task (s,q,row) -> two coalesced 16B stores (h, l fragments)
    #pragma unroll
    for (int i = 0; i < 8; i++) {
        int task = i * 256 + tid;
        int row = task & 127;
        int sq = task >> 7;            // 0..15
        int s = sq >> 1, q = sq & 1;
        float4 lo = *(const float4*)&tf[row * 132 + s * 16 + q * 8];
        float4 hi = *(const float4*)&tf[row * 132 + s * 16 + q * 8 + 4];
        float xs[8] = {lo.x, lo.y, lo.z, lo.w, hi.x, hi.y, hi.z, hi.w};
        ush8 h, l;
        #pragma unroll
        for (int j = 0; j < 8; j++) {
            unsigned short hh = f2bf(xs[j]);
            h[j] = hh;
            l[j] = f2bf(xs[j] - bf2f(hh));
        }
        *(ush8*)(dst + (size_t)((((s * 2 + 0) * 2 + q) * 128) + row) * 16) = h;
        *(ush8*)(dst + (size_t)((((s * 2 + 1) * 2 + q) * 128) + row) * 16) = l;
    }
}

// stage one V tile (+cj slot) with 512 threads into an LDS buffer
__device__ __forceinline__ void stage_tile512(const char* src, char* l, int tid) {
    #pragma unroll
    for (int i = 0; i < 8; i++) {
        int off = (i * 512 + tid) * 16;
        async_cp16(src + off, l + off);
    }
    if (tid < 64) {
        int off = TILE_BYTES + tid * 16;
        async_cp16(src + off, l + off);
    }
}

// ---- K2: staged GEMM, 512 thr / 8 waves / 1 block per CU, double-buffered
// LDS (2x66.5KB). Wave w owns samples [w*32, w*32+32) of the block's 256;
// all 128 codes of each tile. Issue-early: next tile's global_load_lds is
// issued BEFORE the current MFMA chain; single vmcnt(0)+barrier per tile. ----
__global__ __launch_bounds__(512, 2)
void vq_gemm_topk(const float* __restrict__ samples, char* __restrict__ ws) {
    __shared__ __align__(16) char lds[2][TILE_STRIDE];
    const int tid = threadIdx.x;
    const int w = tid >> 6, lane = tid & 63;
    const int l31 = lane & 31, qb = lane >> 5;
    // 256 blocks: chunk pair per XCD slot (bid&7), 16 sample-supertiles
    const int bid = blockIdx.x;
    const int g = bid >> 3;                     // 0..31
    const int chunk = (bid & 7) * 2 + (g >> 4); // 0..15
    const int st = g & 15;                      // 0..15 (256 samples each)
    const int nrow = st * 256 + w * 32 + l31;

    const char* vbase = ws + WS_TILED_BYTE;
    const int tbase = chunk * TILES_PER_CHUNK;

    // prologue: issue stage of tile 0; load B fragments while it flies
    stage_tile512(vbase + (size_t)tbase * TILE_STRIDE, lds[0], tid);
    ush8 bh[8], bl[8];
    load_bfrag(samples, nrow, qb, bh, bl);
    __syncthreads();   // compiler emits vmcnt(0) before barrier: tile 0 ready

    float D1 = FLTMAX, D2 = FLTMAX;
    int T1 = IMAX, T2 = IMAX;

    #pragma unroll 1
    for (int it = 0; it < TILES_PER_CHUNK; it++) {
        const int cur = it & 1;
        if (it + 1 < TILES_PER_CHUNK)
            stage_tile512(vbase + (size_t)(tbase + it + 1) * TILE_STRIDE,
                          lds[cur ^ 1], tid);
        f32x16 acc[4];
        tile_mfma(lds[cur], bh, bl, qb, l31, acc);
        // tile-local top-2 (4 independent chains), then running merge w/ tile id
        float t1[4], t2[4];
        #pragma unroll
        for (int mi = 0; mi < 4; mi++) {
            t1[mi] = FLTMAX; t2[mi] = FLTMAX;
            #pragma unroll
            for (int r = 0; r < 16; r++) {
                float v = acc[mi][r];
                t2[mi] = fminf(t2[mi], fmaxf(t1[mi], v));
                t1[mi] = fminf(t1[mi], v);
            }
        }
        float tt1 = t1[0], tt2 = t2[0];
        #pragma unroll
        for (int mi = 1; mi < 4; mi++) {
            float tmp = fmaxf(tt1, t1[mi]);
            tt1 = fminf(tt1, t1[mi]);
            tt2 = fminf(fminf(tmp, tt2), t2[mi]);
        }
        const int tile = tbase + it;
        bool c1 = tt1 < D1;
        float m1 = fminf(D1, tt2);
        float m2 = fminf(D2, tt1);
        int T2a = (tt2 < D1) ? tile : T1;
        int T2b = (tt1 < D2) ? tile : T2;
        D2 = c1 ? m1 : m2;
        T2 = c1 ? T2a : T2b;
        T1 = c1 ? tile : T1;
        D1 = c1 ? tt1 : D1;
        __syncthreads();   // drain next-tile stage (issued a full phase ago)
    }

    // cross-qb merge (other half-wave: same sample, other code rows)
    {
        float od1 = __shfl_xor(D1, 32), od2 = __shfl_xor(D2, 32);
        int   ot1 = __shfl_xor(T1, 32), ot2 = __shfl_xor(T2, 32);
        merge2t(D1, T1, D2, T2, od1, ot1);
        merge2t(D1, T1, D2, T2, od2, ot2);
    }
    if (qb == 0) {
        float4* part = (float4*)((float*)ws + PART_F);
        part[(size_t)nrow * NCHUNK + chunk] =
            make_float4(D1, D2, (float)T1, (float)T2);
    }
}

// ---- K3: merge chunk partials -> global top-2 values + tile ids; write 'a' ----
__global__ void vq_merge(float* __restrict__ ws_f, float* __restrict__ out) {
    const int m = blockIdx.x * 256 + threadIdx.x;
    int* ws_i = (int*)ws_f;
    const float4* part = (const float4*)(ws_f + PART_F);
    float d1 = FLTMAX, d2 = FLTMAX;
    int t1 = IMAX, t2 = IMAX;
    #pragma unroll
    for (int c = 0; c < NCHUNK; c++) {
        float4 p = part[(size_t)m * NCHUNK + c];
        merge2t(d1, t1, d2, t2, p.x, (int)p.z);
        merge2t(d1, t1, d2, t2, p.y, (int)p.w);
    }
    ((float2*)(ws_f + D12_F))[m] = make_float2(d1, d2);
    ((int2*)(ws_i + T12_I))[m] = make_int2(t1, t2);
    ws_i[CELL1_I + m] = IMAX;
    ws_i[CELL2_I + m] = IMAX;
    float ci = ws_f[XSQ_F + m] + 2.0f * EPSV * ws_f[XSUM_F + m] + (float)DDIM * EPSV * EPSV;
    out[2 * NS + m] = expf(-sqrtf(fmaxf(ci + d1, 0.0f)));
}

// ---- K4: per-tile bit-exact rescan. One block per tile; self-compacts the
// sample list; tile staged to LDS once; indices by float equality;
// atomicMin two-slot insert == reference lowest-index tiebreak ----
__global__ __launch_bounds__(256)
void vq_recover(const float* __restrict__ samples, char* __restrict__ ws) {
    __shared__ __align__(16) char sbuf[TILE_STRIDE];
    __shared__ int list[NS];
    __shared__ int lcnt;
    const int tid = threadIdx.x;
    const int w = tid >> 6, lane = tid & 63;
    const int l31 = lane & 31, qb = lane >> 5;
    const int tile = blockIdx.x;
    int* ws_i = (int*)ws;
    float* ws_f = (float*)ws;

    // issue tile staging first (completes at the barrier below)
    const char* tsrc = ws + WS_TILED_BYTE + (size_t)tile * TILE_STRIDE;
    #pragma unroll
    for (int i = 0; i < 16; i++) {
        int off = (i * 256 + tid) * 16;
        async_cp16(tsrc + off, sbuf + off);
    }
    if (tid < 64) {
        int off = TILE_BYTES + tid * 16;
        async_cp16(tsrc + off, sbuf + off);
    }
    if (tid == 0) lcnt = 0;
    __syncthreads();
    const int2* t12 = (const int2*)(ws_i + T12_I);
    for (int i = tid; i < NS; i += 256) {
        int2 t = t12[i];
        if (t.x == tile || t.y == tile) {
            int p = atomicAdd(&lcnt, 1);
            list[p] = i;
        }
    }
    __syncthreads();
    const int cnt = lcnt;
    if (cnt == 0) return;

    const float2* d12 = (const float2*)(ws_f + D12_F);
    const float nanf_ = __int_as_float(0x7fc00000);

    for (int b0 = 0; b0 < cnt; b0 += 128) {
        int li = b0 + w * 32 + l31;
        bool valid = li < cnt;
        int m = valid ? list[li] : 0;
        ush8 bh[8], bl[8];
        load_bfrag(samples, m, qb, bh, bl);
        float d1t = nanf_, d2t = nanf_;
        if (valid) {
            float2 dt = d12[m];
            d1t = dt.x; d2t = dt.y;
        }
        f32x16 acc[4];
        tile_mfma(sbuf, bh, bl, qb, l31, acc);
        #pragma unroll
        for (int mi = 0; mi < 4; mi++) {
            #pragma unroll
            for (int r = 0; r < 16; r++) {
                float v = acc[mi][r];
                int idx = tile * 128 + mi * 32 + (r & 3) + 8 * (r >> 2) + 4 * qb;
                if (v == d1t) {
                    int old = atomicMin(&ws_i[CELL1_I + m], idx);
                    int loser = old > idx ? old : idx;
                    atomicMin(&ws_i[CELL2_I + m], loser);
                } else if (v == d2t) {
                    atomicMin(&ws_i[CELL2_I + m], idx);
                }
            }
        }
    }
}

// ---- K5: write index outputs ----
__global__ void vq_finalize(const char* __restrict__ ws, float* __restrict__ out) {
    const int m = blockIdx.x * 256 + threadIdx.x;
    const int* ws_i = (const int*)ws;
    out[m]      = (float)ws_i[CELL1_I + m];
    out[NS + m] = (float)ws_i[CELL2_I + m];
}

extern "C" void kernel_launch(void* const* d_in, const int* in_sizes, int n_in,
                              void* d_out, int out_size, void* d_ws, size_t ws_size,
                              hipStream_t stream) {
    (void)in_sizes; (void)n_in; (void)out_size; (void)ws_size;
    const float* samples = (const float*)d_in[0];
    const float* V = (const float*)d_in[1];
    float* out = (float*)d_out;
    float* ws_f = (float*)d_ws;
    char*  ws_b = (char*)d_ws;

    vq_prep<<<dim3(NV / 128 + NS / 4), 256, 0, stream>>>(samples, V, ws_b);
    vq_gemm_topk<<<dim3((NS / 256) * NCHUNK), 512, 0, stream>>>(samples, ws_b);
    vq_merge<<<dim3(NS / 256), 256, 0, stream>>>(ws_f, out);
    vq_recover<<<dim3(NTILE), 256, 0, stream>>>(samples, ws_b);
    vq_finalize<<<dim3(NS / 256), 256, 0, stream>>>(ws_b, out);
}